// Round 1
// baseline (149.085 us; speedup 1.0000x reference)
//
#include <hip/hip_runtime.h>

#define MAX_L 2048   // max phonemes per batch for LDS cumsum
#define MAX_EPC 8    // max cum elements per thread (L <= 256*8)
#define FPB 128      // frames per block (copy kernel)

// ============================================================================
// Kernel A: per-batch duration cumsum + frame -> global feature-row index map.
// gmap[b*T + t] = b*L + p  (phoneme row for frame t), or -1 for pad frames.
// Run-length scatter (thread-per-phoneme) instead of per-frame binary search:
// 512 KiB of int writes total, done once, by 16 blocks.
// ============================================================================
__global__ __launch_bounds__(256) void lr_index_kernel(
        const int* __restrict__ dur,
        const int* __restrict__ tlen,
        int* __restrict__ gmap,
        int BL, int BT) {
    const int T = *tlen;
    const int B = BT / T;
    const int L = BL / B;

    __shared__ int sc[MAX_L];
    __shared__ int swsum[4];

    const int tid  = threadIdx.x;
    const int lane = tid & 63;
    const int wv   = tid >> 6;

    for (int b = blockIdx.x; b < B; b += gridDim.x) {
        __syncthreads();  // protect sc reuse across grid-stride iterations

        // ---- cumsum of batch b's duration row into sc (shuffle scan) ----
        const int epc  = (L + blockDim.x - 1) / blockDim.x;
        const int base = tid * epc;
        const int* __restrict__ drow = dur + (size_t)b * L;
        int local[MAX_EPC];
        int run = 0;
#pragma unroll
        for (int e = 0; e < MAX_EPC; ++e) {
            int v = 0;
            if (e < epc && base + e < L) v = drow[base + e];
            run += v;
            local[e] = run;
        }
        int wsum = run;
#pragma unroll
        for (int off = 1; off < 64; off <<= 1) {
            int up = __shfl_up(wsum, off, 64);
            if (lane >= off) wsum += up;
        }
        if (lane == 63) swsum[wv] = wsum;
        __syncthreads();
        int wprefix = 0;
        for (int w = 0; w < wv; ++w) wprefix += swsum[w];
        const int chunk_prefix = wprefix + wsum - run;
#pragma unroll
        for (int e = 0; e < MAX_EPC; ++e)
            if (e < epc && base + e < L) sc[base + e] = chunk_prefix + local[e];
        __syncthreads();

        const int total_raw = sc[L - 1];
        const int total = total_raw < T ? total_raw : T;
        int* __restrict__ gm = gmap + (size_t)b * T;

        // ---- run-length scatter: phoneme p owns frames [cum[p-1], cum[p]) ----
        // (zero-duration phonemes have empty ranges -> never written, which
        //  exactly matches searchsorted side='right'.)
        for (int p = tid; p < L; p += blockDim.x) {
            int s = p ? sc[p - 1] : 0;
            int e = sc[p];
            if (s > T) s = T;
            if (e > T) e = T;
            const int g = b * L + p;
            for (int t = s; t < e; ++t) gm[t] = g;
        }
        // ---- pad frames past total duration ----
        for (int t = total + tid; t < T; t += blockDim.x) gm[t] = -1;
    }
}

// ============================================================================
// Kernel B: pure streaming copy. No LDS, no barriers, no search.
// One 256-thread block per 128 frames; wave wv owns 32 contiguous frames.
// gmap holds GLOBAL row indices, so batch boundaries are irrelevant here.
// Row data cached in one float4/lane, reloaded only on index change (scalar
// branch via readlane) -> steady state is back-to-back coalesced 1 KiB stores.
// ============================================================================
__global__ __launch_bounds__(256) void lr_copy_kernel(
        const float* __restrict__ feat,
        const int* __restrict__ gmap,
        float* __restrict__ out,
        int BT, int vecs) {
    const long fb = (long)blockIdx.x * FPB;
    if (fb >= BT) return;

    const int tid  = threadIdx.x;
    const int lane = tid & 63;
    const int wv   = tid >> 6;
    const int nf   = (int)(((long)BT - fb) < FPB ? ((long)BT - fb) : (long)FPB);

    if (nf == FPB && vecs == 64) {
        // Fast path (D == 256, full block of frames).
        const long f0 = fb + (long)wv * 32;
        const int si = gmap[f0 + (lane & 31)];  // lane j holds gmap[f0 + j]
        const float4* __restrict__ fv = (const float4*)feat;
        float4* __restrict__ op = (float4*)out + (size_t)f0 * 64 + lane;
        int prev = -2;
        float4 v = make_float4(0.f, 0.f, 0.f, 0.f);
#pragma unroll
        for (int j = 0; j < 32; ++j) {
            const int g = __builtin_amdgcn_readlane(si, j);  // uniform (SGPR)
            if (g != prev) {                                  // scalar branch
                v = (g >= 0) ? fv[(size_t)g * 64 + lane]
                             : make_float4(0.f, 0.f, 0.f, 0.f);
                prev = g;
            }
            op[(size_t)j * 64] = v;   // back-to-back 1 KiB wave stores
        }
    } else {
        // Generic fallback: wave-strided frames, lane-strided float4s.
        const float4 z = make_float4(0.f, 0.f, 0.f, 0.f);
        for (int f = wv; f < nf; f += 4) {
            const int g = gmap[fb + f];
            float4* __restrict__ orow = (float4*)out + (size_t)(fb + f) * vecs;
            if (g >= 0) {
                const float4* __restrict__ irow =
                    (const float4*)feat + (size_t)g * vecs;
                for (int i = lane; i < vecs; i += 64) orow[i] = irow[i];
            } else {
                for (int i = lane; i < vecs; i += 64) orow[i] = z;
            }
        }
    }
}

// ============================================================================
// Fallback: previous harness-verified fused kernel (used if d_ws is too small
// to hold the BT-int index map).
// ============================================================================
__global__ __launch_bounds__(256) void lr_fused_kernel(
        const float* __restrict__ feat,
        const int* __restrict__ dur,
        const int* __restrict__ tlen,
        float* __restrict__ out,
        int BL, int BT, int D) {
    const int T = *tlen;
    const int B = BT / T;
    const int L = BL / B;
    const int vecs = D >> 2;

    __shared__ int sc[MAX_L];
    __shared__ int swsum[4];
    __shared__ int sidx[FPB];

    const long frame_base0 = (long)blockIdx.x * FPB;
    if (frame_base0 >= BT) return;

    const int tid  = threadIdx.x;
    const int lane = tid & 63;
    const int wv   = tid >> 6;

    long fb_ = frame_base0;
    int remaining = (int)((long)BT - frame_base0 < FPB ? (long)BT - frame_base0
                                                       : (long)FPB);

    while (remaining > 0) {
        const int b   = (int)(fb_ / T);
        const int tt0 = (int)(fb_ - (long)b * T);
        const int seg = remaining < (T - tt0) ? remaining : (T - tt0);

        __syncthreads();
        const int epc  = (L + blockDim.x - 1) / blockDim.x;
        const int base = tid * epc;
        const int* __restrict__ drow = dur + (size_t)b * L;
        int local[MAX_EPC];
        int run = 0;
#pragma unroll
        for (int e = 0; e < MAX_EPC; ++e) {
            int v = 0;
            if (e < epc && base + e < L) v = drow[base + e];
            run += v;
            local[e] = run;
        }
        int wsum = run;
#pragma unroll
        for (int off = 1; off < 64; off <<= 1) {
            int up = __shfl_up(wsum, off, 64);
            if (lane >= off) wsum += up;
        }
        if (lane == 63) swsum[wv] = wsum;
        __syncthreads();
        int wprefix = 0;
        for (int w = 0; w < wv; ++w) wprefix += swsum[w];
        const int chunk_prefix = wprefix + wsum - run;
#pragma unroll
        for (int e = 0; e < MAX_EPC; ++e)
            if (e < epc && base + e < L) sc[base + e] = chunk_prefix + local[e];
        __syncthreads();

        const int total = sc[L - 1];

        if (tid < seg) {
            const int t = tt0 + tid;
            int p = -1;
            if (t < total) {
                int lo = 0, hi = L - 1;
                while (lo < hi) {
                    const int mid = (lo + hi) >> 1;
                    if (sc[mid] > t) hi = mid;
                    else             lo = mid + 1;
                }
                p = lo;
            }
            sidx[tid] = p;
        }
        __syncthreads();

        if (seg == FPB && vecs == 64) {
            const float4* __restrict__ fbp =
                (const float4*)feat + (size_t)b * L * 64;
            float4* __restrict__ op =
                (float4*)out + ((size_t)fb_ + (size_t)wv * 32) * 64 + lane;
            const int si = sidx[wv * 32 + (lane & 31)];
            int prev = -2;
            float4 v = make_float4(0.f, 0.f, 0.f, 0.f);
#pragma unroll
            for (int j = 0; j < 32; ++j) {
                const int p = __builtin_amdgcn_readlane(si, j);
                if (p != prev) {
                    v = (p >= 0) ? fbp[(size_t)p * 64 + lane]
                                 : make_float4(0.f, 0.f, 0.f, 0.f);
                    prev = p;
                }
                op[(size_t)j * 64] = v;
            }
        } else {
            const float4* __restrict__ fbp =
                (const float4*)feat + (size_t)b * L * vecs;
            const float4 z = make_float4(0.f, 0.f, 0.f, 0.f);
            for (int f = wv; f < seg; f += 4) {
                const int p = sidx[f];
                float4* __restrict__ orow = (float4*)out + ((size_t)fb_ + f) * vecs;
                if (p >= 0) {
                    const float4* __restrict__ irow = fbp + (size_t)p * vecs;
                    for (int i = lane; i < vecs; i += 64) orow[i] = irow[i];
                } else {
                    for (int i = lane; i < vecs; i += 64) orow[i] = z;
                }
            }
        }

        fb_ += seg;
        remaining -= seg;
    }
}

extern "C" void kernel_launch(void* const* d_in, const int* in_sizes, int n_in,
                              void* d_out, int out_size, void* d_ws, size_t ws_size,
                              hipStream_t stream) {
    const float* feat = (const float*)d_in[0];   // [B, L, D] fp32
    const int*   dur  = (const int*)d_in[1];     // [B, L] int32
    const int*   tlen = (const int*)d_in[2];     // scalar target_length (device)

    const int BL = in_sizes[1];                  // B*L
    const int D  = in_sizes[0] / in_sizes[1];    // feature dim
    const int BT = out_size / D;                 // B*T total frames

    const int grid = (BT + FPB - 1) / FPB;       // 1024 blocks for 16x8192

    if (ws_size >= (size_t)BT * sizeof(int)) {
        // Split path: tiny index-build kernel, then pure streaming copy.
        lr_index_kernel<<<64, 256, 0, stream>>>(dur, tlen, (int*)d_ws, BL, BT);
        lr_copy_kernel<<<grid, 256, 0, stream>>>(feat, (int*)d_ws,
                                                 (float*)d_out, BT, D >> 2);
    } else {
        // Fallback: previous verified fused kernel.
        lr_fused_kernel<<<grid, 256, 0, stream>>>(feat, dur, tlen, (float*)d_out,
                                                  BL, BT, D);
    }
}

// Round 2
// 147.380 us; speedup vs baseline: 1.0116x; 1.0116x over previous
//
#include <hip/hip_runtime.h>

#define MAX_L 2048   // max phonemes per batch for LDS cumsum
#define MAX_EPC 8    // max cum elements per thread (L <= 256*8)
#define FPB 128      // frames per block (copy kernel)
#define SB  16       // frame-slices per batch in the index kernel

// ============================================================================
// Kernel A: frame -> global feature-row index map, full-GPU.
// Work unit = (batch b, slice sl): block recomputes batch b's cumsum (cheap,
// 2 KB + shuffle scan) then per-frame binary-searches its T/SB frame slice,
// storing gmap coalesced. gmap[b*T+t] = b*L+p, or -1 for pad frames.
// Grid-stride over B*SB work units (B unknown on host; read from device).
// ============================================================================
__global__ __launch_bounds__(256) void lr_index_kernel(
        const int* __restrict__ dur,
        const int* __restrict__ tlen,
        int* __restrict__ gmap,
        int BL, int BT) {
    const int T = *tlen;
    const int B = BT / T;
    const int L = BL / B;

    __shared__ int sc[MAX_L];
    __shared__ int swsum[4];

    const int tid  = threadIdx.x;
    const int lane = tid & 63;
    const int wv   = tid >> 6;

    const int nwork = B * SB;
    const int slen  = (T + SB - 1) / SB;

    for (int w = blockIdx.x; w < nwork; w += gridDim.x) {
        const int b  = w / SB;
        const int sl = w - b * SB;

        __syncthreads();  // protect sc reuse across grid-stride iterations

        // ---- cumsum of batch b's duration row into sc (shuffle scan) ----
        const int epc  = (L + blockDim.x - 1) / blockDim.x;
        const int base = tid * epc;
        const int* __restrict__ drow = dur + (size_t)b * L;
        int local[MAX_EPC];
        int run = 0;
#pragma unroll
        for (int e = 0; e < MAX_EPC; ++e) {
            int v = 0;
            if (e < epc && base + e < L) v = drow[base + e];
            run += v;
            local[e] = run;
        }
        int wsum = run;
#pragma unroll
        for (int off = 1; off < 64; off <<= 1) {
            int up = __shfl_up(wsum, off, 64);
            if (lane >= off) wsum += up;
        }
        if (lane == 63) swsum[wv] = wsum;
        __syncthreads();
        int wprefix = 0;
        for (int ww = 0; ww < wv; ++ww) wprefix += swsum[ww];
        const int chunk_prefix = wprefix + wsum - run;
#pragma unroll
        for (int e = 0; e < MAX_EPC; ++e)
            if (e < epc && base + e < L) sc[base + e] = chunk_prefix + local[e];
        __syncthreads();

        const int total = sc[L - 1];
        int* __restrict__ gm = gmap + (size_t)b * T;

        // ---- per-frame searchsorted(side='right') over this slice ----
        const int t0 = sl * slen;
        const int t1 = (t0 + slen) < T ? (t0 + slen) : T;
        for (int t = t0 + tid; t < t1; t += blockDim.x) {
            int g = -1;
            if (t < total) {
                int lo = 0, hi = L - 1;
                while (lo < hi) {
                    const int mid = (lo + hi) >> 1;
                    if (sc[mid] > t) hi = mid;
                    else             lo = mid + 1;
                }
                g = b * L + lo;
            }
            gm[t] = g;   // coalesced int store
        }
    }
}

// ============================================================================
// Kernel B: branchless gather-copy. No LDS, no barriers, no conditional loads.
// Wave wv owns 32 contiguous frames; per frame: readlane(imm) row index ->
// unconditional 1 KiB coalesced row load (L2-resident feat) -> 1 KiB store.
// Iterations are fully independent -> compiler pipelines loads ahead of
// stores; no waitcnt-on-store-path serialization.
// ============================================================================
__global__ __launch_bounds__(256) void lr_copy_kernel(
        const float* __restrict__ feat,
        const int* __restrict__ gmap,
        float* __restrict__ out,
        int BT, int vecs) {
    const long fb = (long)blockIdx.x * FPB;
    if (fb >= BT) return;

    const int tid  = threadIdx.x;
    const int lane = tid & 63;
    const int wv   = tid >> 6;
    const int nf   = (int)(((long)BT - fb) < FPB ? ((long)BT - fb) : (long)FPB);

    if (nf == FPB && vecs == 64) {
        // Fast path (D == 256, full block of frames).
        const long f0 = fb + (long)wv * 32;
        const int si = gmap[f0 + (lane & 31)];  // lane j holds gmap[f0 + j]
        const float4* __restrict__ fv = (const float4*)feat;
        float4* __restrict__ op = (float4*)out + (size_t)f0 * 64 + lane;
#pragma unroll
        for (int j = 0; j < 32; ++j) {
            const int g  = __builtin_amdgcn_readlane(si, j);  // uniform (SGPR)
            const int gc = g < 0 ? 0 : g;                     // clamp for pad
            float4 v = fv[(size_t)gc * 64 + lane];            // unconditional
            if (g < 0) v = make_float4(0.f, 0.f, 0.f, 0.f);   // uniform select
            op[(size_t)j * 64] = v;                           // 1 KiB wave store
        }
    } else {
        // Generic fallback: wave-strided frames, lane-strided float4s.
        const float4 z = make_float4(0.f, 0.f, 0.f, 0.f);
        for (int f = wv; f < nf; f += 4) {
            const int g = gmap[fb + f];
            float4* __restrict__ orow = (float4*)out + (size_t)(fb + f) * vecs;
            if (g >= 0) {
                const float4* __restrict__ irow =
                    (const float4*)feat + (size_t)g * vecs;
                for (int i = lane; i < vecs; i += 64) orow[i] = irow[i];
            } else {
                for (int i = lane; i < vecs; i += 64) orow[i] = z;
            }
        }
    }
}

// ============================================================================
// Fallback: harness-verified fused kernel (used only if d_ws can't hold the
// BT-int index map).
// ============================================================================
__global__ __launch_bounds__(256) void lr_fused_kernel(
        const float* __restrict__ feat,
        const int* __restrict__ dur,
        const int* __restrict__ tlen,
        float* __restrict__ out,
        int BL, int BT, int D) {
    const int T = *tlen;
    const int B = BT / T;
    const int L = BL / B;
    const int vecs = D >> 2;

    __shared__ int sc[MAX_L];
    __shared__ int swsum[4];
    __shared__ int sidx[FPB];

    const long frame_base0 = (long)blockIdx.x * FPB;
    if (frame_base0 >= BT) return;

    const int tid  = threadIdx.x;
    const int lane = tid & 63;
    const int wv   = tid >> 6;

    long fb_ = frame_base0;
    int remaining = (int)((long)BT - frame_base0 < FPB ? (long)BT - frame_base0
                                                       : (long)FPB);

    while (remaining > 0) {
        const int b   = (int)(fb_ / T);
        const int tt0 = (int)(fb_ - (long)b * T);
        const int seg = remaining < (T - tt0) ? remaining : (T - tt0);

        __syncthreads();
        const int epc  = (L + blockDim.x - 1) / blockDim.x;
        const int base = tid * epc;
        const int* __restrict__ drow = dur + (size_t)b * L;
        int local[MAX_EPC];
        int run = 0;
#pragma unroll
        for (int e = 0; e < MAX_EPC; ++e) {
            int v = 0;
            if (e < epc && base + e < L) v = drow[base + e];
            run += v;
            local[e] = run;
        }
        int wsum = run;
#pragma unroll
        for (int off = 1; off < 64; off <<= 1) {
            int up = __shfl_up(wsum, off, 64);
            if (lane >= off) wsum += up;
        }
        if (lane == 63) swsum[wv] = wsum;
        __syncthreads();
        int wprefix = 0;
        for (int w = 0; w < wv; ++w) wprefix += swsum[w];
        const int chunk_prefix = wprefix + wsum - run;
#pragma unroll
        for (int e = 0; e < MAX_EPC; ++e)
            if (e < epc && base + e < L) sc[base + e] = chunk_prefix + local[e];
        __syncthreads();

        const int total = sc[L - 1];

        if (tid < seg) {
            const int t = tt0 + tid;
            int p = -1;
            if (t < total) {
                int lo = 0, hi = L - 1;
                while (lo < hi) {
                    const int mid = (lo + hi) >> 1;
                    if (sc[mid] > t) hi = mid;
                    else             lo = mid + 1;
                }
                p = lo;
            }
            sidx[tid] = p;
        }
        __syncthreads();

        if (seg == FPB && vecs == 64) {
            const float4* __restrict__ fbp =
                (const float4*)feat + (size_t)b * L * 64;
            float4* __restrict__ op =
                (float4*)out + ((size_t)fb_ + (size_t)wv * 32) * 64 + lane;
            const int si = sidx[wv * 32 + (lane & 31)];
#pragma unroll
            for (int j = 0; j < 32; ++j) {
                const int p  = __builtin_amdgcn_readlane(si, j);
                const int pc = p < 0 ? 0 : p;
                float4 v = fbp[(size_t)pc * 64 + lane];
                if (p < 0) v = make_float4(0.f, 0.f, 0.f, 0.f);
                op[(size_t)j * 64] = v;
            }
        } else {
            const float4* __restrict__ fbp =
                (const float4*)feat + (size_t)b * L * vecs;
            const float4 z = make_float4(0.f, 0.f, 0.f, 0.f);
            for (int f = wv; f < seg; f += 4) {
                const int p = sidx[f];
                float4* __restrict__ orow = (float4*)out + ((size_t)fb_ + f) * vecs;
                if (p >= 0) {
                    const float4* __restrict__ irow = fbp + (size_t)p * vecs;
                    for (int i = lane; i < vecs; i += 64) orow[i] = irow[i];
                } else {
                    for (int i = lane; i < vecs; i += 64) orow[i] = z;
                }
            }
        }

        fb_ += seg;
        remaining -= seg;
    }
}

extern "C" void kernel_launch(void* const* d_in, const int* in_sizes, int n_in,
                              void* d_out, int out_size, void* d_ws, size_t ws_size,
                              hipStream_t stream) {
    const float* feat = (const float*)d_in[0];   // [B, L, D] fp32
    const int*   dur  = (const int*)d_in[1];     // [B, L] int32
    const int*   tlen = (const int*)d_in[2];     // scalar target_length (device)

    const int BL = in_sizes[1];                  // B*L
    const int D  = in_sizes[0] / in_sizes[1];    // feature dim
    const int BT = out_size / D;                 // B*T total frames

    const int grid = (BT + FPB - 1) / FPB;       // 1024 blocks for 16x8192

    if (ws_size >= (size_t)BT * sizeof(int)) {
        // Split path: full-GPU index build, then branchless streaming gather.
        lr_index_kernel<<<256, 256, 0, stream>>>(dur, tlen, (int*)d_ws, BL, BT);
        lr_copy_kernel<<<grid, 256, 0, stream>>>(feat, (int*)d_ws,
                                                 (float*)d_out, BT, D >> 2);
    } else {
        // Fallback: verified fused kernel (branchless copy variant).
        lr_fused_kernel<<<grid, 256, 0, stream>>>(feat, dur, tlen, (float*)d_out,
                                                  BL, BT, D);
    }
}